// Round 1
// baseline (76.525 us; speedup 1.0000x reference)
//
#include <hip/hip_runtime.h>

#define LORENZ_DT 0.02f

__device__ __forceinline__ void lorenz_one(float x0, float x1, float x2,
                                           float& o0, float& o1, float& o2) {
    // A*dt; only a12/a21 depend on x0. a02 = a20 = 0 structurally.
    const float a00 = -10.0f * LORENZ_DT;
    const float a01 =  10.0f * LORENZ_DT;
    const float a10 =  28.0f * LORENZ_DT;
    const float a11 =  -1.0f * LORENZ_DT;
    const float a22 = (-8.0f / 3.0f) * LORENZ_DT;
    const float a12 = -x0 * LORENZ_DT;
    const float a21 =  x0 * LORENZ_DT;

    // F = I + sum_{j=1..5} (A dt)^j / j!, term recurrence: t <- (t @ A dt)/j
    float t00 = 1.f, t01 = 0.f, t02 = 0.f;
    float t10 = 0.f, t11 = 1.f, t12 = 0.f;
    float t20 = 0.f, t21 = 0.f, t22 = 1.f;
    float F00 = 1.f, F01 = 0.f, F02 = 0.f;
    float F10 = 0.f, F11 = 1.f, F12 = 0.f;
    float F20 = 0.f, F21 = 0.f, F22 = 1.f;

#pragma unroll
    for (int j = 1; j <= 5; ++j) {
        const float inv = 1.0f / (float)j;  // folds to a literal after unroll
        // new[i][k] = sum_m t[i][m] * A[m][k]   (A col 0 has a20=0; col 2 has a02=0)
        float n00 = (t00 * a00 + t01 * a10) * inv;
        float n01 = (t00 * a01 + t01 * a11 + t02 * a21) * inv;
        float n02 = (t01 * a12 + t02 * a22) * inv;
        float n10 = (t10 * a00 + t11 * a10) * inv;
        float n11 = (t10 * a01 + t11 * a11 + t12 * a21) * inv;
        float n12 = (t11 * a12 + t12 * a22) * inv;
        float n20 = (t20 * a00 + t21 * a10) * inv;
        float n21 = (t20 * a01 + t21 * a11 + t22 * a21) * inv;
        float n22 = (t21 * a12 + t22 * a22) * inv;
        t00 = n00; t01 = n01; t02 = n02;
        t10 = n10; t11 = n11; t12 = n12;
        t20 = n20; t21 = n21; t22 = n22;
        F00 += t00; F01 += t01; F02 += t02;
        F10 += t10; F11 += t11; F12 += t12;
        F20 += t20; F21 += t21; F22 += t22;
    }

    o0 = F00 * x0 + F01 * x1 + F02 * x2;
    o1 = F10 * x0 + F11 * x1 + F12 * x2;
    o2 = F20 * x0 + F21 * x1 + F22 * x2;
}

// Each thread processes 4 batch elements = 12 floats = 3 float4 loads/stores.
__global__ __launch_bounds__(256) void lorenz_kernel(const float* __restrict__ x,
                                                     float* __restrict__ out, int n) {
    const int g = blockIdx.x * blockDim.x + threadIdx.x;  // group of 4 elements
    const int base = g * 4;
    if (base >= n) return;

    if (base + 4 <= n) {
        const float4* xv = (const float4*)x;
        float4* ov = (float4*)out;
        float4 va = xv[g * 3 + 0];
        float4 vb = xv[g * 3 + 1];
        float4 vc = xv[g * 3 + 2];
        float xs[12] = {va.x, va.y, va.z, va.w,
                        vb.x, vb.y, vb.z, vb.w,
                        vc.x, vc.y, vc.z, vc.w};
        float os[12];
#pragma unroll
        for (int e = 0; e < 4; ++e) {
            lorenz_one(xs[e * 3 + 0], xs[e * 3 + 1], xs[e * 3 + 2],
                       os[e * 3 + 0], os[e * 3 + 1], os[e * 3 + 2]);
        }
        ov[g * 3 + 0] = make_float4(os[0], os[1], os[2], os[3]);
        ov[g * 3 + 1] = make_float4(os[4], os[5], os[6], os[7]);
        ov[g * 3 + 2] = make_float4(os[8], os[9], os[10], os[11]);
    } else {
        // scalar tail (n not divisible by 4)
        for (int e = base; e < n; ++e) {
            float x0 = x[e * 3 + 0], x1 = x[e * 3 + 1], x2 = x[e * 3 + 2];
            float o0, o1, o2;
            lorenz_one(x0, x1, x2, o0, o1, o2);
            out[e * 3 + 0] = o0;
            out[e * 3 + 1] = o1;
            out[e * 3 + 2] = o2;
        }
    }
}

extern "C" void kernel_launch(void* const* d_in, const int* in_sizes, int n_in,
                              void* d_out, int out_size, void* d_ws, size_t ws_size,
                              hipStream_t stream) {
    const float* x = (const float*)d_in[0];
    float* out = (float*)d_out;
    const int n = in_sizes[0] / 3;          // batch count (2,000,000)
    const int groups = (n + 3) / 4;         // 4 elements per thread
    const int block = 256;
    const int grid = (groups + block - 1) / block;
    lorenz_kernel<<<grid, block, 0, stream>>>(x, out, n);
}